// Round 15
// baseline (270.471 us; speedup 1.0000x reference)
//
#include <hip/hip_runtime.h>
#include <hip/hip_fp16.h>
#include <math.h>

// Problem constants
#define BATCH 256
#define CIN 3
#define HW 128
#define OC 16
#define POOLED 63
#define FEAT 63504         // OC*63*63
#define NH 256
#define FANIN 512
#define NO 10

#define PADX 134           // LDS x-stride in halves
#define ROWS 12            // (c,dy) rows
#define SMEM_BYTES (ROWS * 16 * PADX * 2)   // 51,456
#define NBLK 512u

typedef _Float16 h4 __attribute__((ext_vector_type(4)));
typedef _Float16 h2v __attribute__((ext_vector_type(2)));
typedef float    f4 __attribute__((ext_vector_type(4)));

// Software grid barrier (graph-capture-safe replacement for grid.sync()).
// Residency proof: LDS 51,456B -> >=2 blocks/CU (102,912<=163,840), 4 waves/blk
// -> <=12 waves/CU << 32; capacity >= 512 blocks => dispatcher makes ALL blocks
// resident immediately => spin cannot deadlock. thread-0 release-fence
// (__threadfence = agent scope; gfx950 L2 writeback => cross-XCD visibility of
// the preceding normal stores) + device-scope atomicAdd + ACQUIRE spin.
__device__ __forceinline__ void grid_barrier(unsigned* cnt) {
    __syncthreads();
    if (threadIdx.x == 0) {
        __threadfence();
        atomicAdd(cnt, 1u);
        while (__hip_atomic_load(cnt, __ATOMIC_ACQUIRE, __HIP_MEMORY_SCOPE_AGENT) < NBLK) {
            __builtin_amdgcn_s_sleep(8);
        }
    }
    __syncthreads();
}

// ---------------- Fused pipeline: conv+pool | gbar | hidden | gbar | out --------
// R14's cooperative launch was rejected under graph capture (out stayed zero:
// absmax 0.7656 == max|ref|). Same experiment, capture-safe barrier. Phase
// bodies are FROZEN R12 code. Conv tile map keeps the XCD write-pairing: block
// bid (XCD bid%8, R10-verified) handles tiles with g in {2u,2u+1}.
__global__ __launch_bounds__(256) void fused_kernel(const float* __restrict__ inp,
                                                    const float* __restrict__ cw,
                                                    const float* __restrict__ cb,
                                                    const int* __restrict__ hidx,
                                                    const float* __restrict__ hw,
                                                    const float* __restrict__ hb,
                                                    const float* __restrict__ ow,
                                                    const float* __restrict__ ob,
                                                    __half* __restrict__ featsT,
                                                    float* __restrict__ hiddenP,
                                                    unsigned* __restrict__ bar,
                                                    float* __restrict__ out) {
    __shared__ __align__(16) char smem[SMEM_BYTES];
    const int bid = blockIdx.x;
    const int t   = threadIdx.x;

    // ================= Phase 1: conv3x3+bias+relu+maxpool (MFMA, R12 body) ======
    {
        _Float16* sB = (_Float16*)smem;
        const int l    = t & 63;
        const int w    = t >> 6;
        const int q    = l >> 4;
        const int bcol = l & 15;
        const int u    = bid & 7;

        h4  aF[3][2];
        int bOff[3][2];
        float bias[4];
#pragma unroll
        for (int s = 0; s < 3; ++s) {
            const int rIdx = s * 4 + q;
            const int c    = (rIdx * 11) >> 5;
            const int ky   = rIdx - 3 * c;
            const bool valid = (c < 3);
            float wv[3];
#pragma unroll
            for (int kx = 0; kx < 3; ++kx)
                wv[kx] = valid ? cw[(bcol * CIN + c) * 9 + ky * 3 + kx] : 0.0f;
            aF[s][0][0] = (_Float16)wv[0]; aF[s][0][1] = (_Float16)wv[1];
            aF[s][0][2] = (_Float16)wv[2]; aF[s][0][3] = (_Float16)0.0f;
            aF[s][1][0] = (_Float16)0.0f;  aF[s][1][1] = (_Float16)wv[0];
            aF[s][1][2] = (_Float16)wv[1]; aF[s][1][3] = (_Float16)wv[2];
#pragma unroll
            for (int ys = 0; ys < 2; ++ys) {
                const int row = valid ? (c * 4 + ys + ky) : ys;
                bOff[s][ys] = (row * 16 + bcol) * PADX;
            }
        }
#pragma unroll
        for (int r = 0; r < 4; ++r) bias[r] = cb[4 * q + r];

#pragma unroll 1
        for (int tt = bid >> 3; tt < 126; tt += 64) {
            const int i  = tt >> 1;
            const int g  = 2 * u + (tt & 1);
            const int y0 = 2 * i;

            __syncthreads();
#pragma unroll
            for (int bb = 0; bb < 4; ++bb) {
                const int b_l = w * 4 + bb;
#pragma unroll
                for (int rr = 0; rr < 12; ++rr) {
                    const int c  = rr >> 2;
                    const int dy = rr & 3;
                    const float2 vv = *(const float2*)
                        &inp[((size_t)(g * 16 + b_l) * CIN + c) * (HW * HW) + (y0 + dy) * HW + 2 * l];
                    *(__half2*)&sB[(size_t)((c * 4 + dy) * 16 + b_l) * PADX + 2 * l] =
                        __float22half2_rn(vv);
                }
            }
            __syncthreads();

            const int jend = (16 * w + 16 < 63) ? (16 * w + 16) : 63;
            for (int j = 16 * w; j < jend; ++j) {
                f4 d00 = {0.f,0.f,0.f,0.f}, d01 = d00, d10 = d00, d11 = d00;
#pragma unroll
                for (int s = 0; s < 3; ++s) {
                    const _Float16* p0 = &sB[bOff[s][0] + 2 * j];
                    const _Float16* p1 = &sB[bOff[s][1] + 2 * j];
                    const h2v a0 = *(const h2v*)p0, a1 = *(const h2v*)(p0 + 2);
                    const h2v c0 = *(const h2v*)p1, c1 = *(const h2v*)(p1 + 2);
                    const h4 bF0 = {a0[0], a0[1], a1[0], a1[1]};
                    const h4 bF1 = {c0[0], c0[1], c1[0], c1[1]};
                    d00 = __builtin_amdgcn_mfma_f32_16x16x16f16(aF[s][0], bF0, d00, 0, 0, 0);
                    d01 = __builtin_amdgcn_mfma_f32_16x16x16f16(aF[s][1], bF0, d01, 0, 0, 0);
                    d10 = __builtin_amdgcn_mfma_f32_16x16x16f16(aF[s][0], bF1, d10, 0, 0, 0);
                    d11 = __builtin_amdgcn_mfma_f32_16x16x16f16(aF[s][1], bF1, d11, 0, 0, 0);
                }
#pragma unroll
                for (int r = 0; r < 4; ++r) {
                    const float mv = fmaxf(fmaxf(d00[r], d01[r]), fmaxf(d10[r], d11[r]));
                    const float rv = fmaxf(mv + bias[r], 0.0f);
                    const int oc = 4 * q + r;
                    featsT[(size_t)(oc * 3969 + i * POOLED + j) * BATCH + g * 16 + bcol] =
                        __float2half_rn(rv);
                }
            }
        }
    }

    grid_barrier(&bar[0]);

    // ================= Phase 2: sparse hidden (R12 16B-gather body) =============
    {
        int*   sidx = (int*)smem;
        float* swt  = (float*)(smem + 512);
        float (*red)[256] = (float (*)[256])(smem + 1024);
        const int l   = t & 63;
        const int w   = t >> 6;
        const int hl  = l & 31;
        const int sel = l >> 5;

#pragma unroll 1
        for (int unit = bid; unit < 1024; unit += NBLK) {
            const int h = unit & 255;
            const int q = unit >> 8;
            __syncthreads();
            if (t < 128) {
                sidx[t] = hidx[h * FANIN + q * 128 + t];
                swt[t]  = hw[h * FANIN + q * 128 + t];
            }
            __syncthreads();

            float acc[8] = {0.f,0.f,0.f,0.f,0.f,0.f,0.f,0.f};
#pragma unroll
            for (int m = 0; m < 16; ++m) {
                const int kloc = w * 32 + 2 * m + sel;
                const uint4 v = *(const uint4*)(featsT + (size_t)sidx[kloc] * BATCH + 8 * hl);
                const __half2* hp = reinterpret_cast<const __half2*>(&v);
                const float wt = swt[kloc];
#pragma unroll
                for (int d2 = 0; d2 < 4; ++d2) {
                    const float2 f = __half22float2(hp[d2]);
                    acc[2 * d2 + 0] += f.x * wt;
                    acc[2 * d2 + 1] += f.y * wt;
                }
            }
#pragma unroll
            for (int e = 0; e < 8; ++e) acc[e] += __shfl_xor(acc[e], 32);
            if (sel == 0) {
#pragma unroll
                for (int e = 0; e < 8; ++e) red[w][8 * hl + e] = acc[e];
            }
            __syncthreads();

            if (t < 256) {
                const float s = red[0][t] + red[1][t] + red[2][t] + red[3][t];
                hiddenP[((size_t)q * NH + h) * BATCH + t] = s;
            }
        }
    }

    grid_barrier(&bar[1]);

    // ================= Phase 3: partial-sum + sigmoid + dense out (R12 body) ====
    if (bid < 160) {
        float* red = (float*)smem;
        const int o  = bid >> 4;
        const int bt = bid & 15;
        const int tb = t & 15;
        const int hg = t >> 4;
        const int b  = bt * 16 + tb;
        float acc = 0.f;
#pragma unroll
        for (int k = 0; k < 16; ++k) {
            const int h = hg * 16 + k;
            const float s = hiddenP[(0 * NH + h) * BATCH + b]
                          + hiddenP[(1 * NH + h) * BATCH + b]
                          + hiddenP[(2 * NH + h) * BATCH + b]
                          + hiddenP[(3 * NH + h) * BATCH + b] + hb[h];
            const float hs = 1.0f / (1.0f + __expf(-s));
            acc += hs * ow[o * NH + h];
        }
        __syncthreads();
        red[t] = acc;
        __syncthreads();
        if (hg == 0) {
            float s = 0.f;
#pragma unroll
            for (int gg = 0; gg < 16; ++gg) s += red[gg * 16 + tb];
            out[b * NO + o] = 1.0f / (1.0f + __expf(-(s + ob[o])));
        }
    }
}

extern "C" void kernel_launch(void* const* d_in, const int* in_sizes, int n_in,
                              void* d_out, int out_size, void* d_ws, size_t ws_size,
                              hipStream_t stream) {
    const float* inputs   = (const float*)d_in[0];
    const float* conv_w   = (const float*)d_in[1];
    const float* conv_b   = (const float*)d_in[2];
    const int*   hidden_i = (const int*)d_in[3];
    const float* hidden_w = (const float*)d_in[4];
    const float* hidden_b = (const float*)d_in[5];
    const float* out_w    = (const float*)d_in[6];
    const float* out_b    = (const float*)d_in[7];
    float* out = (float*)d_out;

    char* ws = (char*)d_ws;
    __half*   featsT  = (__half*)ws;                                     // 32,514,048 B
    float*    hiddenP = (float*)(ws + (size_t)FEAT * BATCH * 2);         //  1,048,576 B
    unsigned* bar     = (unsigned*)(ws + (size_t)FEAT * BATCH * 2
                                       + (size_t)4 * NH * BATCH * 4);    // 64B, 64-aligned

    // zero the two barrier counters (in-stream; replays with the graph)
    hipMemsetAsync(bar, 0, 64, stream);

    fused_kernel<<<NBLK, 256, 0, stream>>>(inputs, conv_w, conv_b,
                                           hidden_i, hidden_w, hidden_b,
                                           out_w, out_b,
                                           featsT, hiddenP, bar, out);
}

// Round 16
// 195.075 us; speedup vs baseline: 1.3865x; 1.3865x over previous
//
#include <hip/hip_runtime.h>
#include <hip/hip_fp16.h>
#include <math.h>

// Problem constants
#define BATCH 256
#define CIN 3
#define HW 128
#define OC 16
#define POOLED 63
#define FEAT 63504         // OC*63*63
#define NH 256
#define FANIN 512
#define NO 10

#define PADX 134           // LDS x-stride in halves
#define ROWS 12            // (c,dy) rows

typedef _Float16 h4 __attribute__((ext_vector_type(4)));
typedef _Float16 h2v __attribute__((ext_vector_type(2)));
typedef float    f4 __attribute__((ext_vector_type(4)));

// ---------------- Kernel 1: conv3x3+bias+relu+maxpool via MFMA (FROZEN R12) ------
__global__ __launch_bounds__(256) void conv_pool_kernel(const float* __restrict__ inp,
                                                        const float* __restrict__ cw,
                                                        const float* __restrict__ cb,
                                                        __half* __restrict__ featsT) {
    __shared__ _Float16 sB[ROWS * 16 * PADX];     // 51,456 B
    const int t    = threadIdx.x;
    const int l    = t & 63;
    const int w    = t >> 6;
    const int q    = l >> 4;
    const int bcol = l & 15;

    const int id = blockIdx.x;
    const int u  = id & 7;
    const int v  = id >> 3;
    const int i  = v >> 1;
    const int g  = 2 * u + (v & 1);
    const int y0 = 2 * i;

#pragma unroll
    for (int bb = 0; bb < 4; ++bb) {
        const int b_l = w * 4 + bb;
#pragma unroll
        for (int rr = 0; rr < 12; ++rr) {
            const int c  = rr >> 2;
            const int dy = rr & 3;
            const float2 vv = *(const float2*)
                &inp[((size_t)(g * 16 + b_l) * CIN + c) * (HW * HW) + (y0 + dy) * HW + 2 * l];
            *(__half2*)&sB[(size_t)((c * 4 + dy) * 16 + b_l) * PADX + 2 * l] =
                __float22half2_rn(vv);
        }
    }
    __syncthreads();

    h4  aF[3][2];
    int bOff[3][2];
    float bias[4];
#pragma unroll
    for (int s = 0; s < 3; ++s) {
        const int rIdx = s * 4 + q;
        const int c    = (rIdx * 11) >> 5;
        const int ky   = rIdx - 3 * c;
        const bool valid = (c < 3);
        float wv[3];
#pragma unroll
        for (int kx = 0; kx < 3; ++kx)
            wv[kx] = valid ? cw[(bcol * CIN + c) * 9 + ky * 3 + kx] : 0.0f;
        aF[s][0][0] = (_Float16)wv[0]; aF[s][0][1] = (_Float16)wv[1];
        aF[s][0][2] = (_Float16)wv[2]; aF[s][0][3] = (_Float16)0.0f;
        aF[s][1][0] = (_Float16)0.0f;  aF[s][1][1] = (_Float16)wv[0];
        aF[s][1][2] = (_Float16)wv[1]; aF[s][1][3] = (_Float16)wv[2];
#pragma unroll
        for (int ys = 0; ys < 2; ++ys) {
            const int row = valid ? (c * 4 + ys + ky) : ys;
            bOff[s][ys] = (row * 16 + bcol) * PADX;
        }
    }
#pragma unroll
    for (int r = 0; r < 4; ++r) bias[r] = cb[4 * q + r];

    const int jend = (16 * w + 16 < 63) ? (16 * w + 16) : 63;
    for (int j = 16 * w; j < jend; ++j) {
        f4 d00 = {0.f,0.f,0.f,0.f}, d01 = d00, d10 = d00, d11 = d00;
#pragma unroll
        for (int s = 0; s < 3; ++s) {
            const _Float16* p0 = &sB[bOff[s][0] + 2 * j];
            const _Float16* p1 = &sB[bOff[s][1] + 2 * j];
            const h2v a0 = *(const h2v*)p0, a1 = *(const h2v*)(p0 + 2);
            const h2v c0 = *(const h2v*)p1, c1 = *(const h2v*)(p1 + 2);
            const h4 bF0 = {a0[0], a0[1], a1[0], a1[1]};
            const h4 bF1 = {c0[0], c0[1], c1[0], c1[1]};
            d00 = __builtin_amdgcn_mfma_f32_16x16x16f16(aF[s][0], bF0, d00, 0, 0, 0);
            d01 = __builtin_amdgcn_mfma_f32_16x16x16f16(aF[s][1], bF0, d01, 0, 0, 0);
            d10 = __builtin_amdgcn_mfma_f32_16x16x16f16(aF[s][0], bF1, d10, 0, 0, 0);
            d11 = __builtin_amdgcn_mfma_f32_16x16x16f16(aF[s][1], bF1, d11, 0, 0, 0);
        }
#pragma unroll
        for (int r = 0; r < 4; ++r) {
            const float mv = fmaxf(fmaxf(d00[r], d01[r]), fmaxf(d10[r], d11[r]));
            const float rv = fmaxf(mv + bias[r], 0.0f);
            const int oc = 4 * q + r;
            featsT[(size_t)(oc * 3969 + i * POOLED + j) * BATCH + g * 16 + bcol] =
                __float2half_rn(rv);
        }
    }
}

// ---------------- Kernel 2: hidden (R12 body) + last-block output tail ----------
// R15 decomposition: pipeline work ~17us busy; the ~93us non-fill residual is
// dominated by dispatch-boundary + latency costs. Reduce kernel count 3->2:
// out_kernel is absorbed as a COMPLETION-DETECTION tail (not a barrier -- no
// spin, no deadlock risk): each block finishes its (h,q) unit, release-fence +
// RELAXED atomicAdd; the single block seeing old==1023 does ONE acquire load
// (one cache-invalidate in the whole kernel) and computes the 10x256 output
// (~5us on one block). 1023 blocks exit immediately.
__global__ __launch_bounds__(256) void hidden_out_kernel(const __half* __restrict__ featsT,
                                                         const int* __restrict__ hidx,
                                                         const float* __restrict__ hw,
                                                         const float* __restrict__ hb,
                                                         const float* __restrict__ ow,
                                                         const float* __restrict__ ob,
                                                         float* __restrict__ hiddenP,
                                                         unsigned* __restrict__ cnt,
                                                         float* __restrict__ out) {
    __shared__ int   sidx[128];
    __shared__ float swt[128];
    __shared__ float red[4][256];
    __shared__ int   lastFlag;
    const int bid = blockIdx.x;     // 0..1023
    const int h   = bid & 255;
    const int q   = bid >> 8;
    const int t   = threadIdx.x;
    if (t < 128) {
        sidx[t] = hidx[h * FANIN + q * 128 + t];
        swt[t]  = hw[h * FANIN + q * 128 + t];
    }
    __syncthreads();

    const int l   = t & 63;
    const int w   = t >> 6;
    const int hl  = l & 31;
    const int sel = l >> 5;
    float acc[8] = {0.f,0.f,0.f,0.f,0.f,0.f,0.f,0.f};
#pragma unroll
    for (int m = 0; m < 16; ++m) {
        const int kloc = w * 32 + 2 * m + sel;
        const uint4 v = *(const uint4*)(featsT + (size_t)sidx[kloc] * BATCH + 8 * hl);
        const __half2* hp = reinterpret_cast<const __half2*>(&v);
        const float wt = swt[kloc];
#pragma unroll
        for (int d2 = 0; d2 < 4; ++d2) {
            const float2 f = __half22float2(hp[d2]);
            acc[2 * d2 + 0] += f.x * wt;
            acc[2 * d2 + 1] += f.y * wt;
        }
    }
#pragma unroll
    for (int e = 0; e < 8; ++e) acc[e] += __shfl_xor(acc[e], 32);
    if (sel == 0) {
#pragma unroll
        for (int e = 0; e < 8; ++e) red[w][8 * hl + e] = acc[e];
    }
    __syncthreads();

    if (t < 256) {
        const float s = red[0][t] + red[1][t] + red[2][t] + red[3][t];
        hiddenP[((size_t)q * NH + h) * BATCH + t] = s;
    }

    // ---- completion detection (no spin) ----
    __syncthreads();                 // drains this block's hiddenP stores
    if (t == 0) {
        __threadfence();             // release: write back dirty L2 (cross-XCD vis)
        const unsigned old = __hip_atomic_fetch_add(cnt, 1u, __ATOMIC_RELAXED,
                                                    __HIP_MEMORY_SCOPE_AGENT);
        if (old == 1023u) {
            // single acquire: invalidate stale lines before reading hiddenP
            (void)__hip_atomic_load(cnt, __ATOMIC_ACQUIRE, __HIP_MEMORY_SCOPE_AGENT);
            lastFlag = 1;
        } else {
            lastFlag = 0;
        }
    }
    __syncthreads();
    if (!lastFlag) return;

    // ---- output tail: this block computes all 10x256 outputs ----
    const int b = t;                 // 0..255
    float oacc[NO];
#pragma unroll
    for (int o = 0; o < NO; ++o) oacc[o] = 0.f;
#pragma unroll 4
    for (int hh = 0; hh < NH; ++hh) {
        const float s = hiddenP[(0 * NH + hh) * BATCH + b]
                      + hiddenP[(1 * NH + hh) * BATCH + b]
                      + hiddenP[(2 * NH + hh) * BATCH + b]
                      + hiddenP[(3 * NH + hh) * BATCH + b] + hb[hh];
        const float hs = 1.0f / (1.0f + __expf(-s));
#pragma unroll
        for (int o = 0; o < NO; ++o) oacc[o] += hs * ow[o * NH + hh];
    }
#pragma unroll
    for (int o = 0; o < NO; ++o)
        out[b * NO + o] = 1.0f / (1.0f + __expf(-(oacc[o] + ob[o])));
}

extern "C" void kernel_launch(void* const* d_in, const int* in_sizes, int n_in,
                              void* d_out, int out_size, void* d_ws, size_t ws_size,
                              hipStream_t stream) {
    const float* inputs   = (const float*)d_in[0];
    const float* conv_w   = (const float*)d_in[1];
    const float* conv_b   = (const float*)d_in[2];
    const int*   hidden_i = (const int*)d_in[3];
    const float* hidden_w = (const float*)d_in[4];
    const float* hidden_b = (const float*)d_in[5];
    const float* out_w    = (const float*)d_in[6];
    const float* out_b    = (const float*)d_in[7];
    float* out = (float*)d_out;

    char* ws = (char*)d_ws;
    __half*   featsT  = (__half*)ws;                                     // 32,514,048 B
    float*    hiddenP = (float*)(ws + (size_t)FEAT * BATCH * 2);         //  1,048,576 B
    unsigned* cnt     = (unsigned*)(ws + (size_t)FEAT * BATCH * 2
                                       + (size_t)4 * NH * BATCH * 4);    // 64 B

    hipMemsetAsync(cnt, 0, 64, stream);   // zero the completion counter (in-stream)

    conv_pool_kernel<<<1008, 256, 0, stream>>>(inputs, conv_w, conv_b, featsT);
    hidden_out_kernel<<<1024, 256, 0, stream>>>(featsT, hidden_i, hidden_w, hidden_b,
                                                out_w, out_b, hiddenP, cnt, out);
}

// Round 17
// 129.622 us; speedup vs baseline: 2.0866x; 1.5050x over previous
//
#include <hip/hip_runtime.h>
#include <hip/hip_fp16.h>
#include <math.h>

// Problem constants
#define BATCH 256
#define CIN 3
#define HW 128
#define OC 16
#define POOLED 63
#define FEAT 63504         // OC*63*63
#define NH 256
#define FANIN 512
#define NO 10

#define PADX 134           // LDS x-stride in halves
#define ROWS 12            // (c,dy) rows

typedef _Float16 h4 __attribute__((ext_vector_type(4)));
typedef _Float16 h2v __attribute__((ext_vector_type(2)));
typedef float    f4 __attribute__((ext_vector_type(4)));

// ---------------- Kernel 1: conv3x3+bias+relu+maxpool via MFMA (R12 + NT stores) -
// R16 decomposition: hidden body ~40-45us = the largest kernel, bound by the
// cross-XCD dirty handoff of featsT (conv leaves 32.5MB dirty across 8
// non-coherent L2s; hidden's random gathers force remote-L2 writeback->L3->read
// per line -- explains why bytes/2, blocks x4, instrs /2, XCD-locality were ALL
// null). Single change vs R12: featsT stored NONTEMPORAL (gfx950 'nt': evict-
// first, no dirty L2 residency) -> lines land clean in L3; hidden reads clean
// L3 hits, no on-demand remote writeback storm.
__global__ __launch_bounds__(256) void conv_pool_kernel(const float* __restrict__ inp,
                                                        const float* __restrict__ cw,
                                                        const float* __restrict__ cb,
                                                        __half* __restrict__ featsT) {
    __shared__ _Float16 sB[ROWS * 16 * PADX];     // 51,456 B
    const int t    = threadIdx.x;
    const int l    = t & 63;
    const int w    = t >> 6;        // wave 0..3
    const int q    = l >> 4;        // quarter 0..3
    const int bcol = l & 15;        // oc for A/D, batch-col for B

    // block decode: g-pairs (2u,2u+1) share featsT 64B lines AND the XCD
    const int id = blockIdx.x;
    const int u  = id & 7;
    const int v  = id >> 3;          // 0..125
    const int i  = v >> 1;           // pooled row 0..62
    const int g  = 2 * u + (v & 1);  // batch group 0..15
    const int y0 = 2 * i;

    // ---- stage: rows (c,dy) x 16 b -> f16, coalesced float2 per lane ----
#pragma unroll
    for (int bb = 0; bb < 4; ++bb) {
        const int b_l = w * 4 + bb;
#pragma unroll
        for (int rr = 0; rr < 12; ++rr) {
            const int c  = rr >> 2;
            const int dy = rr & 3;
            const float2 vv = *(const float2*)
                &inp[((size_t)(g * 16 + b_l) * CIN + c) * (HW * HW) + (y0 + dy) * HW + 2 * l];
            *(__half2*)&sB[(size_t)((c * 4 + dy) * 16 + b_l) * PADX + 2 * l] =
                __float22half2_rn(vv);
        }
    }
    __syncthreads();

    // ---- per-lane A fragments and B base offsets ----
    h4  aF[3][2];                   // [s][xs]
    int bOff[3][2];                 // [s][ys]
    float bias[4];
#pragma unroll
    for (int s = 0; s < 3; ++s) {
        const int rIdx = s * 4 + q;            // 0..11
        const int c    = (rIdx * 11) >> 5;     // /3
        const int ky   = rIdx - 3 * c;
        const bool valid = (c < 3);
        float wv[3];
#pragma unroll
        for (int kx = 0; kx < 3; ++kx)
            wv[kx] = valid ? cw[(bcol * CIN + c) * 9 + ky * 3 + kx] : 0.0f;
        aF[s][0][0] = (_Float16)wv[0]; aF[s][0][1] = (_Float16)wv[1];
        aF[s][0][2] = (_Float16)wv[2]; aF[s][0][3] = (_Float16)0.0f;
        aF[s][1][0] = (_Float16)0.0f;  aF[s][1][1] = (_Float16)wv[0];
        aF[s][1][2] = (_Float16)wv[1]; aF[s][1][3] = (_Float16)wv[2];
#pragma unroll
        for (int ys = 0; ys < 2; ++ys) {
            const int row = valid ? (c * 4 + ys + ky) : ys;
            bOff[s][ys] = (row * 16 + bcol) * PADX;
        }
    }
#pragma unroll
    for (int r = 0; r < 4; ++r) bias[r] = cb[4 * q + r];

    // ---- pooled-col loop ----
    const int jend = (16 * w + 16 < 63) ? (16 * w + 16) : 63;
    for (int j = 16 * w; j < jend; ++j) {
        f4 d00 = {0.f,0.f,0.f,0.f}, d01 = d00, d10 = d00, d11 = d00;
#pragma unroll
        for (int s = 0; s < 3; ++s) {
            const _Float16* p0 = &sB[bOff[s][0] + 2 * j];
            const _Float16* p1 = &sB[bOff[s][1] + 2 * j];
            const h2v a0 = *(const h2v*)p0, a1 = *(const h2v*)(p0 + 2);
            const h2v c0 = *(const h2v*)p1, c1 = *(const h2v*)(p1 + 2);
            const h4 bF0 = {a0[0], a0[1], a1[0], a1[1]};
            const h4 bF1 = {c0[0], c0[1], c1[0], c1[1]};
            d00 = __builtin_amdgcn_mfma_f32_16x16x16f16(aF[s][0], bF0, d00, 0, 0, 0);
            d01 = __builtin_amdgcn_mfma_f32_16x16x16f16(aF[s][1], bF0, d01, 0, 0, 0);
            d10 = __builtin_amdgcn_mfma_f32_16x16x16f16(aF[s][0], bF1, d10, 0, 0, 0);
            d11 = __builtin_amdgcn_mfma_f32_16x16x16f16(aF[s][1], bF1, d11, 0, 0, 0);
        }
#pragma unroll
        for (int r = 0; r < 4; ++r) {
            const float mv = fmaxf(fmaxf(d00[r], d01[r]), fmaxf(d10[r], d11[r]));
            const float rv = fmaxf(mv + bias[r], 0.0f);
            const int oc = 4 * q + r;
            const __half hv = __float2half_rn(rv);
            __builtin_nontemporal_store(
                *(const short*)&hv,
                (short*)&featsT[(size_t)(oc * 3969 + i * POOLED + j) * BATCH + g * 16 + bcol]);
        }
    }
}

// ---------------- Kernel 2: sparse hidden layer, 16B gather (FROZEN R12) --------
__global__ __launch_bounds__(256) void hidden_kernel(const __half* __restrict__ featsT,
                                                     const int* __restrict__ hidx,
                                                     const float* __restrict__ hw,
                                                     float* __restrict__ hiddenP) {
    __shared__ int   sidx[128];
    __shared__ float swt[128];
    __shared__ float red[4][256];
    const int h = blockIdx.x;
    const int q = blockIdx.y;
    const int t = threadIdx.x;
    if (t < 128) {
        sidx[t] = hidx[h * FANIN + q * 128 + t];
        swt[t]  = hw[h * FANIN + q * 128 + t];
    }
    __syncthreads();

    const int l   = t & 63;
    const int w   = t >> 6;          // 0..3
    const int hl  = l & 31;
    const int sel = l >> 5;
    float acc[8] = {0.f,0.f,0.f,0.f,0.f,0.f,0.f,0.f};
#pragma unroll
    for (int m = 0; m < 16; ++m) {
        const int kloc = w * 32 + 2 * m + sel;
        const uint4 v = *(const uint4*)(featsT + (size_t)sidx[kloc] * BATCH + 8 * hl);
        const __half2* hp = reinterpret_cast<const __half2*>(&v);
        const float wt = swt[kloc];
#pragma unroll
        for (int d2 = 0; d2 < 4; ++d2) {
            const float2 f = __half22float2(hp[d2]);
            acc[2 * d2 + 0] += f.x * wt;
            acc[2 * d2 + 1] += f.y * wt;
        }
    }
#pragma unroll
    for (int e = 0; e < 8; ++e) acc[e] += __shfl_xor(acc[e], 32);
    if (sel == 0) {
#pragma unroll
        for (int e = 0; e < 8; ++e) red[w][8 * hl + e] = acc[e];
    }
    __syncthreads();

    if (t < 256) {
        const float s = red[0][t] + red[1][t] + red[2][t] + red[3][t];
        hiddenP[((size_t)q * NH + h) * BATCH + t] = s;
    }
}

// ---------------- Kernel 3: partial-sum + sigmoid + dense 256->10 (FROZEN R12) --
__global__ __launch_bounds__(256) void out_kernel(const float* __restrict__ hiddenP,
                                                  const float* __restrict__ hb,
                                                  const float* __restrict__ ow,
                                                  const float* __restrict__ ob,
                                                  float* __restrict__ out) {
    __shared__ float red[256];
    const int o  = blockIdx.x;
    const int bt = blockIdx.y;
    const int tb = threadIdx.x & 15;
    const int hg = threadIdx.x >> 4;
    const int b  = bt * 16 + tb;
    float acc = 0.f;
#pragma unroll
    for (int k = 0; k < 16; ++k) {
        const int h = hg * 16 + k;
        const float s = hiddenP[(0 * NH + h) * BATCH + b]
                      + hiddenP[(1 * NH + h) * BATCH + b]
                      + hiddenP[(2 * NH + h) * BATCH + b]
                      + hiddenP[(3 * NH + h) * BATCH + b] + hb[h];
        const float hs = 1.0f / (1.0f + __expf(-s));
        acc += hs * ow[o * NH + h];
    }
    red[threadIdx.x] = acc;
    __syncthreads();
    if (hg == 0) {
        float s = 0.f;
#pragma unroll
        for (int gg = 0; gg < 16; ++gg) s += red[gg * 16 + tb];
        out[b * NO + o] = 1.0f / (1.0f + __expf(-(s + ob[o])));
    }
}

extern "C" void kernel_launch(void* const* d_in, const int* in_sizes, int n_in,
                              void* d_out, int out_size, void* d_ws, size_t ws_size,
                              hipStream_t stream) {
    const float* inputs   = (const float*)d_in[0];
    const float* conv_w   = (const float*)d_in[1];
    const float* conv_b   = (const float*)d_in[2];
    const int*   hidden_i = (const int*)d_in[3];
    const float* hidden_w = (const float*)d_in[4];
    const float* hidden_b = (const float*)d_in[5];
    const float* out_w    = (const float*)d_in[6];
    const float* out_b    = (const float*)d_in[7];
    float* out = (float*)d_out;

    char* ws = (char*)d_ws;
    __half* featsT  = (__half*)ws;                                  // 32,514,048 B
    float*  hiddenP = (float*)(ws + (size_t)FEAT * BATCH * 2);      //  1,048,576 B

    conv_pool_kernel<<<1008, 256, 0, stream>>>(inputs, conv_w, conv_b, featsT);
    hidden_kernel<<<dim3(NH, 4), 256, 0, stream>>>(featsT, hidden_i, hidden_w, hiddenP);
    out_kernel<<<dim3(NO, 16), 256, 0, stream>>>(hiddenP, hidden_b, out_w, out_b, out);
}